// Round 6
// baseline (378.682 us; speedup 1.0000x reference)
//
#include <hip/hip_runtime.h>
#include <cstdint>
#include <cstddef>
#include <cstdio>

// ---------------------------------------------------------------------------
// TransformerLayer on MI355X (gfx950), bf16 MFMA everywhere.
// b=2, L=2048, d=1024, d_ff=3072, nh=16, D_HEAD=64.
// Round 6: attention with (a) k-pair-permuted Vt so V-frags load as b128
// (conflict-free, K-pattern shape), (b) 32 q/wave via intra-block k-split
// (waves split each 64-k tile; O/rowsum merged once at end through LDS).
// down-proj: BN=128 split-K2 with fp32 atomicAdd onto the residual buffer.
// ---------------------------------------------------------------------------

typedef unsigned short u16;
typedef __bf16 bf16x8 __attribute__((ext_vector_type(8)));
typedef short  s16x4  __attribute__((ext_vector_type(4)));
typedef short  s16x8  __attribute__((ext_vector_type(8)));
typedef float  f32x4  __attribute__((ext_vector_type(4)));

__device__ __forceinline__ u16 f2b(float f) {
  return __builtin_bit_cast(u16, (__bf16)f);
}
__device__ __forceinline__ float b2f(u16 u) {
  return (float)__builtin_bit_cast(__bf16, u);
}

// async global->LDS, 16B per lane. LDS dest must be wave-uniform base + lane*16.
__device__ __forceinline__ void cp16(const u16* g, u16* l) {
  __builtin_amdgcn_global_load_lds(
      (__attribute__((address_space(1))) void*)(uintptr_t)g,
      (__attribute__((address_space(3))) void*)(uintptr_t)l,
      16, 0, 0);
}

// ---------------------------------------------------------------------------
// GEMM: C[M,N] = A[M,K] @ B[N,K]^T  (A row stride = lda, B row stride = K)
// A, B bf16; C fp32 (MODE 0), fp32 + residual (MODE 1), bf16 (MODE 2),
// fp32 atomicAdd (MODE 3, for split-K via gridDim.z; C must be pre-filled
// with the residual/zero).
// 128xBN tile (BN=128 or 64), BK=64, 4 waves, 16x16x32 MFMA, XOR-swizzled LDS.
// ---------------------------------------------------------------------------
template <int MODE, int BN>
__global__ __launch_bounds__(256) void gemm_bt(
    const u16* __restrict__ A, const u16* __restrict__ B,
    float* __restrict__ Cf, u16* __restrict__ Cb, const float* __restrict__ res,
    int M, int N, int K, int lda)
{
  constexpr int NI = BN / 32;          // acc cols per wave
  __shared__ __align__(16) u16 lsA[128 * 64];
  __shared__ __align__(16) u16 lsB[BN * 64];
  const int t = threadIdx.x;
  const int w = t >> 6, lane = t & 63;
  const int wm = (w >> 1) * 64, wn = (w & 1) * (BN / 2);
  const int lr = lane & 15, quad = lane >> 4;
  const int cswz = lr & 7;
  const size_t rowA0 = (size_t)blockIdx.x * 128;
  const size_t rowB0 = (size_t)blockIdx.y * BN;
  const int kpb = K / (int)gridDim.z;          // K-range per z-slice
  const int kz0 = (int)blockIdx.z * kpb;

  f32x4 acc[4][NI] = {};

  for (int k0 = kz0; k0 < kz0 + kpb; k0 += 64) {
#pragma unroll
    for (int i = 0; i < 4; ++i) {
      const int id = i * 256 + t;
      const int r = id >> 3;
      const int c = ((id & 7) ^ (r & 7)) * 8;  // swizzled source column
      cp16(A + (rowA0 + r) * lda + k0 + c, lsA + id * 8);
    }
#pragma unroll
    for (int i = 0; i < BN / 32; ++i) {
      const int id = i * 256 + t;
      const int r = id >> 3;
      const int c = ((id & 7) ^ (r & 7)) * 8;
      cp16(B + (rowB0 + r) * (size_t)K + k0 + c, lsB + id * 8);
    }
    __syncthreads();
#pragma unroll
    for (int ks = 0; ks < 2; ++ks) {
      const int co = ((ks * 4 + quad) ^ cswz) * 8;
      bf16x8 af[4], bfr[NI];
#pragma unroll
      for (int i = 0; i < 4; ++i)
        af[i] = *(const bf16x8*)(lsA + (wm + i * 16 + lr) * 64 + co);
#pragma unroll
      for (int i = 0; i < NI; ++i)
        bfr[i] = *(const bf16x8*)(lsB + (wn + i * 16 + lr) * 64 + co);
#pragma unroll
      for (int mi = 0; mi < 4; ++mi)
#pragma unroll
        for (int ni = 0; ni < NI; ++ni)
          acc[mi][ni] = __builtin_amdgcn_mfma_f32_16x16x32_bf16(
              af[mi], bfr[ni], acc[mi][ni], 0, 0, 0);
    }
    __syncthreads();
  }

#pragma unroll
  for (int mi = 0; mi < 4; ++mi) {
#pragma unroll
    for (int r = 0; r < 4; ++r) {
      const size_t m = rowA0 + wm + mi * 16 + quad * 4 + r;
#pragma unroll
      for (int ni = 0; ni < NI; ++ni) {
        const size_t n = rowB0 + wn + ni * 16 + lr;
        const size_t o = m * (size_t)N + n;
        const float v = acc[mi][ni][r];
        if (MODE == 0) Cf[o] = v;
        else if (MODE == 1) Cf[o] = v + res[o];
        else if (MODE == 2) Cb[o] = f2b(v);
        else atomicAdd(&Cf[o], v);
      }
    }
  }
}

// ---------------------------------------------------------------------------
// RMSNorm: one block per row of 1024; fp32 in, bf16 out.
// ---------------------------------------------------------------------------
__global__ __launch_bounds__(256) void rmsnorm_k(
    const float* __restrict__ x, const float* __restrict__ g, u16* __restrict__ out)
{
  const int row = blockIdx.x;
  const int t = threadIdx.x;
  const float4 a = ((const float4*)(x + (size_t)row * 1024))[t];
  float ss = a.x * a.x + a.y * a.y + a.z * a.z + a.w * a.w;
#pragma unroll
  for (int o = 32; o; o >>= 1) ss += __shfl_xor(ss, o, 64);
  __shared__ float red[4];
  if ((t & 63) == 0) red[t >> 6] = ss;
  __syncthreads();
  ss = red[0] + red[1] + red[2] + red[3];
  const float r = rsqrtf(ss * (1.0f / 1024.0f) + 1e-6f);
  const float4 gg = ((const float4*)g)[t];
  ushort4 o4;
  o4.x = f2b(a.x * gg.x * r);
  o4.y = f2b(a.y * gg.y * r);
  o4.z = f2b(a.z * gg.z * r);
  o4.w = f2b(a.w * gg.w * r);
  ((ushort4*)out)[(size_t)row * 256 + t] = o4;
}

// fp32 -> bf16 weight conversion, 4 elems/thread.
__global__ __launch_bounds__(256) void cvt_bf16_k(
    const float* __restrict__ in, u16* __restrict__ out)
{
  const size_t i = (size_t)blockIdx.x * 256 + threadIdx.x;
  const float4 v = ((const float4*)in)[i];
  ushort4 o4;
  o4.x = f2b(v.x); o4.y = f2b(v.y); o4.z = f2b(v.z); o4.w = f2b(v.w);
  ((ushort4*)out)[i] = o4;
}

// ---------------------------------------------------------------------------
// QKV prep (bf16 input): per (n,h,l) cosine-normalize q,k; write Q,K as
// [head][l][64] bf16, V transposed as [head][e][L] bf16 with k-PAIR-PERMUTED
// 64-blocks: within each 64-col block, stored 16B chunk c holds k-units
// 8*(c>>2)+(c&3) and +4 (unit = 4 consecutive k). This makes the attention
// V-fragment read a single b128 per (ei, k-half) -> conflict-free.
// Grid (L/64, nh, n), block 256.
// ---------------------------------------------------------------------------
__global__ __launch_bounds__(256) void qkv_prep_k(
    const u16* __restrict__ qkv, const float* __restrict__ attn_scale,
    u16* __restrict__ Qb, u16* __restrict__ Kb, u16* __restrict__ Vt)
{
  const int l0 = blockIdx.x * 64;
  const int h  = blockIdx.y;
  const int nb = blockIdx.z;
  const int t = threadIdx.x, w = t >> 6, lane = t & 63;
  __shared__ float lsV[64][65];  // +1 pad: conflict-free transposed reads
  const float sq = sqrtf(attn_scale[h]);
  const int head = nb * 16 + h;
#pragma unroll 4
  for (int i = 0; i < 16; ++i) {
    const int lrow = i * 4 + w;
    const int l = l0 + lrow;
    const u16* base = qkv + ((size_t)nb * 2048 + l) * 3072 + h * 64 + lane;
    const float qv = b2f(base[0]);
    const float kv = b2f(base[1024]);
    const float vv = b2f(base[2048]);
    float ssq = qv * qv, ssk = kv * kv;
#pragma unroll
    for (int o = 32; o; o >>= 1) {
      ssq += __shfl_xor(ssq, o, 64);
      ssk += __shfl_xor(ssk, o, 64);
    }
    const size_t gb = ((size_t)head * 2048 + l) * 64 + lane;
    Qb[gb] = f2b(qv * sq * rsqrtf(ssq + 1e-6f));
    Kb[gb] = f2b(kv * sq * rsqrtf(ssk + 1e-6f));
    lsV[lrow][lane] = vv;
  }
  __syncthreads();
  const int e = t >> 2, p = t & 3;
  union { u16 s[16]; uint4 v[2]; } tmp;
#pragma unroll
  for (int cc = 0; cc < 2; ++cc) {
    const int c = 2 * p + cc;
    const int kb = 32 * (c >> 2) + 4 * (c & 3);
#pragma unroll
    for (int i = 0; i < 4; ++i) {
      tmp.s[cc * 8 + i]     = f2b(lsV[kb + i][e]);
      tmp.s[cc * 8 + 4 + i] = f2b(lsV[kb + 16 + i][e]);
    }
  }
  u16* dst = Vt + ((size_t)head * 64 + e) * 2048 + l0 + p * 16;
  *(uint4*)dst = tmp.v[0];
  *(uint4*)(dst + 8) = tmp.v[1];
}

// ---------------------------------------------------------------------------
// Attention, round 6. Block = 64 q; 4 waves: wave w handles q-half qh=w>>1
// (32 q) and k-half kh=w&1 (32 of each 64-k tile). Per tile per wave:
//   2x [K-frag b128 x2 -> S^T 16x16x32 MFMA x2qb -> exp -> pf]
//   4x [V-frag b128 (k-pair-permuted Vt) -> PV 16x16x16 x2qb x2ktl]
// Partial O^T/rowsum merged across kh pairs through LDS at the end.
// S^T C-layout == B-operand layout of 16x16x16 => P never touches LDS.
// LDS: 2*(8K+8K) dbuf = 32 KB (merge reuses it). Grid (32, 32) -> 4 bl/CU.
// Scores bounded [-10,10] by cosine norm -> no max-tracking.
// ---------------------------------------------------------------------------
__global__ __launch_bounds__(256) void attn_k(
    const u16* __restrict__ Qb, const u16* __restrict__ Kb,
    const u16* __restrict__ Vt, u16* __restrict__ O)
{
  const int l0 = blockIdx.x * 64;
  const int head = blockIdx.y;
  const int nb = head >> 4, h = head & 15;
  const int t = threadIdx.x, w = t >> 6, lane = t & 63;
  const int lr = lane & 15, quad = lane >> 4;
  const int kh = w & 1, qh = w >> 1;
  __shared__ __align__(16) u16 lsKV[2][2][64 * 64];  // [buf][K=0/V=1]
  const size_t hb = (size_t)head << 17;  // head * 2048 * 64

  // staging: thread t owns LDS chunk t (row t>>3, slot t&7); loads global
  // chunk (t&7)^(row&7) so logical chunk lc of row r lives at lc^(r&7).
  const int sr = t >> 3;
  const int sc = ((t & 7) ^ (sr & 7)) * 8;
  const u16* Kg = Kb + hb + (size_t)sr * 64 + sc;
  const u16* Vg = Vt + hb + (size_t)sr * 2048 + sc;

  // Q fragments (B-operand of S^T): q = l0 + qh*32 + qb*16 + lr, e = quad*8+j.
  bf16x8 qf[2][2];
#pragma unroll
  for (int qb = 0; qb < 2; ++qb) {
    const u16* qp = Qb + hb + (size_t)(l0 + qh * 32 + qb * 16 + lr) * 64 + quad * 8;
    qf[qb][0] = *(const bf16x8*)qp;
    qf[qb][1] = *(const bf16x8*)(qp + 32);
  }

  f32x4 ot[2][4] = {};    // O^T partial: ot[qb][ei][r] = O^T[ei*16+quad*4+r][q]
  float rs[2] = {0.f, 0.f};

  // prologue: stage tile 0 into buf 0
  cp16(Kg, lsKV[0][0] + t * 8);
  cp16(Kg + 32 * 64, lsKV[0][0] + 32 * 64 + t * 8);
  cp16(Vg, lsKV[0][1] + t * 8);
  cp16(Vg + 32 * 2048, lsKV[0][1] + 32 * 64 + t * 8);

  int cur = 0;
  for (int k0 = 0; k0 < 2048; k0 += 64) {
    __syncthreads();  // buf[cur] staged; alt buf's readers done
    if (k0 + 64 < 2048) {
      const int nxt = cur ^ 1;
      const u16* Kn = Kg + (size_t)(k0 + 64) * 64;
      const u16* Vn = Vg + (k0 + 64);
      cp16(Kn, lsKV[nxt][0] + t * 8);
      cp16(Kn + 32 * 64, lsKV[nxt][0] + 32 * 64 + t * 8);
      cp16(Vn, lsKV[nxt][1] + t * 8);
      cp16(Vn + 32 * 2048, lsKV[nxt][1] + 32 * 64 + t * 8);
    }
    const u16* kb = lsKV[cur][0];
    const u16* vb = lsKV[cur][1];

    // S^T for this wave's k-half: kt = kh*2 + ktl
    s16x4 pf[2][2];  // [qb][ktl]
#pragma unroll
    for (int ktl = 0; ktl < 2; ++ktl) {
      const int kt = kh * 2 + ktl;
      const int krow = (kt * 16 + lr) * 64;
      const int kswz = lr & 7;
      const bf16x8 a0 = *(const bf16x8*)(kb + krow + ((quad ^ kswz) << 3));
      const bf16x8 a1 = *(const bf16x8*)(kb + krow + (((4 + quad) ^ kswz) << 3));
#pragma unroll
      for (int qb = 0; qb < 2; ++qb) {
        f32x4 s = {};
        s = __builtin_amdgcn_mfma_f32_16x16x32_bf16(a0, qf[qb][0], s, 0, 0, 0);
        s = __builtin_amdgcn_mfma_f32_16x16x32_bf16(a1, qf[qb][1], s, 0, 0, 0);
#pragma unroll
        for (int r = 0; r < 4; ++r) {
          const float p = __expf(s[r]);
          rs[qb] += p;
          pf[qb][ktl][r] = (short)f2b(p);
        }
      }
    }
    // PV: one b128 per ei gives V A-frags for BOTH ktl (k-pair-permuted Vt).
#pragma unroll
    for (int ei = 0; ei < 4; ++ei) {
      const int vrow = ei * 16 + lr;
      const s16x8 vv = *(const s16x8*)(vb + vrow * 64 + (((kh * 4 + quad) ^ (vrow & 7)) << 3));
      const s16x4 v0 = __builtin_shufflevector(vv, vv, 0, 1, 2, 3);
      const s16x4 v1 = __builtin_shufflevector(vv, vv, 4, 5, 6, 7);
#pragma unroll
      for (int qb = 0; qb < 2; ++qb) {
        ot[qb][ei] = __builtin_amdgcn_mfma_f32_16x16x16bf16_1k(v0, pf[qb][0], ot[qb][ei], 0, 0, 0);
        ot[qb][ei] = __builtin_amdgcn_mfma_f32_16x16x16bf16_1k(v1, pf[qb][1], ot[qb][ei], 0, 0, 0);
      }
    }
    cur ^= 1;
  }

  // intra-wave rowsum reduce across quads (lanes sharing q = lr)
#pragma unroll
  for (int qb = 0; qb < 2; ++qb) {
    rs[qb] += __shfl_xor(rs[qb], 16, 64);
    rs[qb] += __shfl_xor(rs[qb], 32, 64);
  }

  // merge k-halves: waves kh=1 publish partials, kh=0 finalize.
  __syncthreads();  // all tile reads done; LDS reusable
  float* mb = (float*)lsKV;  // (2 qh * 64 lanes) * 34 floats = 17.4 KB < 32 KB
  if (kh == 1) {
    float* dst = mb + (qh * 64 + lane) * 34;
#pragma unroll
    for (int qb = 0; qb < 2; ++qb)
#pragma unroll
      for (int ei = 0; ei < 4; ++ei)
#pragma unroll
        for (int r = 0; r < 4; ++r)
          dst[qb * 16 + ei * 4 + r] = ot[qb][ei][r];
    dst[32] = rs[0];
    dst[33] = rs[1];
  }
  __syncthreads();
  if (kh == 0) {
    const float* src = mb + (qh * 64 + lane) * 34;
#pragma unroll
    for (int qb = 0; qb < 2; ++qb) {
      const float inv = 1.0f / (rs[qb] + src[32 + qb]);
      u16* ob = O + ((size_t)nb * 2048 + l0 + qh * 32 + qb * 16 + lr) * 1024 + h * 64 + quad * 4;
#pragma unroll
      for (int ei = 0; ei < 4; ++ei) {
        ushort4 o4;
        o4.x = f2b((ot[qb][ei][0] + src[qb * 16 + ei * 4 + 0]) * inv);
        o4.y = f2b((ot[qb][ei][1] + src[qb * 16 + ei * 4 + 1]) * inv);
        o4.z = f2b((ot[qb][ei][2] + src[qb * 16 + ei * 4 + 2]) * inv);
        o4.w = f2b((ot[qb][ei][3] + src[qb * 16 + ei * 4 + 3]) * inv);
        *(ushort4*)(ob + ei * 16) = o4;
      }
    }
  }
}

// ---------------------------------------------------------------------------
// SwiGLU, in-place on u[4096][6144] bf16: u[:, :3072] = a * silu(g).
// ---------------------------------------------------------------------------
__global__ __launch_bounds__(256) void swiglu_k(u16* __restrict__ u)
{
  const unsigned j = ((unsigned)blockIdx.x * 256 + threadIdx.x) * 8;
  const unsigned row = j / 3072u, col = j % 3072u;
  u16* ap = u + (size_t)row * 6144 + col;
  union { u16 s[8]; uint4 v; } a, g, hh;
  a.v = *(const uint4*)ap;
  g.v = *(const uint4*)(ap + 3072);
#pragma unroll
  for (int i = 0; i < 8; ++i) {
    const float av = b2f(a.s[i]);
    const float gv = b2f(g.s[i]);
    hh.s[i] = f2b(av * (gv / (1.0f + __expf(-gv))));
  }
  *(uint4*)ap = hh.v;
}

// ---------------------------------------------------------------------------
// Workspace layout (bytes).
// ---------------------------------------------------------------------------
static constexpr size_t WQKV_B = 0;                            // 3072*1024*2
static constexpr size_t WOUT_B = WQKV_B + 6291456;             // 1024*1024*2
static constexpr size_t WUP_B  = WOUT_B + 2097152;             // 6144*1024*2
static constexpr size_t WDN_B  = WUP_B + 12582912;             // 1024*3072*2
static constexpr size_t XN_B   = WDN_B + 6291456;              // 4096*1024*2
static constexpr size_t Q_B    = XN_B + 8388608;               // 32*2048*64*2
static constexpr size_t K_B    = Q_B + 8388608;
static constexpr size_t VT_B   = K_B + 8388608;
static constexpr size_t O_B    = VT_B + 8388608;               // 4096*1024*2
static constexpr size_t BIG_B  = O_B + 8388608;                // qkv bf16 / u bf16
static constexpr size_t WS_NEED = BIG_B + 50331648;            // = 119537664

extern "C" void kernel_launch(void* const* d_in, const int* in_sizes, int n_in,
                              void* d_out, int out_size, void* d_ws, size_t ws_size,
                              hipStream_t stream)
{
  (void)in_sizes; (void)n_in; (void)out_size;
  if (ws_size < WS_NEED) {
    fprintf(stderr, "kernel_launch: ws_size %zu < required %zu\n", ws_size, WS_NEED);
    return;
  }
  const float* x          = (const float*)d_in[0];
  const float* norm_scale = (const float*)d_in[2];
  const float* w_qkv      = (const float*)d_in[3];
  const float* attn_scale = (const float*)d_in[4];
  const float* w_out      = (const float*)d_in[5];
  const float* ff_scale   = (const float*)d_in[6];
  const float* w_up       = (const float*)d_in[7];
  const float* w_down     = (const float*)d_in[8];
  float* out = (float*)d_out;
  char* ws = (char*)d_ws;

  u16* wqkv_b = (u16*)(ws + WQKV_B);
  u16* wout_b = (u16*)(ws + WOUT_B);
  u16* wup_b  = (u16*)(ws + WUP_B);
  u16* wdn_b  = (u16*)(ws + WDN_B);
  u16* xn     = (u16*)(ws + XN_B);
  u16* Qb     = (u16*)(ws + Q_B);
  u16* Kb     = (u16*)(ws + K_B);
  u16* Vtb    = (u16*)(ws + VT_B);
  u16* Ob     = (u16*)(ws + O_B);
  u16* qkvb   = (u16*)(ws + BIG_B);  // qkv bf16 (25 MB), later reused for u
  u16* ub     = (u16*)(ws + BIG_B);

  // weights fp32 -> bf16
  cvt_bf16_k<<<3072, 256, 0, stream>>>(w_qkv, wqkv_b);
  cvt_bf16_k<<<1024, 256, 0, stream>>>(w_out, wout_b);
  cvt_bf16_k<<<6144, 256, 0, stream>>>(w_up,  wup_b);
  cvt_bf16_k<<<3072, 256, 0, stream>>>(w_down, wdn_b);

  // xn = rmsnorm(x)
  rmsnorm_k<<<4096, 256, 0, stream>>>(x, norm_scale, xn);
  // qkv = xn @ w_qkv^T  (bf16 out)
  gemm_bt<2, 128><<<dim3(32, 24), 256, 0, stream>>>(xn, wqkv_b, nullptr, qkvb,
                                                    nullptr, 4096, 3072, 1024, 1024);
  // q/k cosine norm + head-major layouts + V transpose (k-pair-permuted)
  qkv_prep_k<<<dim3(32, 16, 2), 256, 0, stream>>>(qkvb, attn_scale, Qb, Kb, Vtb);
  // attention -> O bf16 [n][l][d]
  attn_k<<<dim3(32, 32), 256, 0, stream>>>(Qb, Kb, Vtb, Ob);
  // x1 = O @ w_out^T + x  -> d_out (fp32); BN=64 for occupancy (N=1024)
  gemm_bt<1, 64><<<dim3(32, 16), 256, 0, stream>>>(Ob, wout_b, out, nullptr, x,
                                                   4096, 1024, 1024, 1024);
  // xn = rmsnorm(x1)
  rmsnorm_k<<<4096, 256, 0, stream>>>(out, ff_scale, xn);
  // u = xn @ w_up^T  (bf16 out, 4096x6144)  -- overwrites qkvb region
  gemm_bt<2, 128><<<dim3(32, 48), 256, 0, stream>>>(xn, wup_b, nullptr, ub, nullptr,
                                                    4096, 6144, 1024, 1024);
  // h = a * silu(g), in-place into u[:, :3072]
  swiglu_k<<<6144, 256, 0, stream>>>(ub);
  // out += h @ w_down^T  (split-K2, atomicAdd onto out which holds x1)
  gemm_bt<3, 128><<<dim3(32, 8, 2), 256, 0, stream>>>(ub, wdn_b, out, nullptr,
                                                      nullptr, 4096, 1024, 3072, 6144);
}

// Round 7
// 351.483 us; speedup vs baseline: 1.0774x; 1.0774x over previous
//
#include <hip/hip_runtime.h>
#include <cstdint>
#include <cstddef>
#include <cstdio>

// ---------------------------------------------------------------------------
// TransformerLayer on MI355X (gfx950), bf16 MFMA everywhere.
// b=2, L=2048, d=1024, d_ff=3072, nh=16, D_HEAD=64.
// Round 7: (a) SwiGLU fused into the up-GEMM epilogue (dual a/g accumulators,
// h written directly -- kills the 50MB u round-trip), (b) down-proj reverted
// to MODE 1 BN=64 (r6's split-K atomics were a 10us regression),
// (c) 4 weight-cvt launches merged into 1. Attention kept from r6
// (k-split waves + k-pair-permuted Vt, conflict-free b128 V-frags).
// ---------------------------------------------------------------------------

typedef unsigned short u16;
typedef __bf16 bf16x8 __attribute__((ext_vector_type(8)));
typedef short  s16x4  __attribute__((ext_vector_type(4)));
typedef short  s16x8  __attribute__((ext_vector_type(8)));
typedef float  f32x4  __attribute__((ext_vector_type(4)));

__device__ __forceinline__ u16 f2b(float f) {
  return __builtin_bit_cast(u16, (__bf16)f);
}
__device__ __forceinline__ float b2f(u16 u) {
  return (float)__builtin_bit_cast(__bf16, u);
}

// async global->LDS, 16B per lane. LDS dest must be wave-uniform base + lane*16.
__device__ __forceinline__ void cp16(const u16* g, u16* l) {
  __builtin_amdgcn_global_load_lds(
      (__attribute__((address_space(1))) void*)(uintptr_t)g,
      (__attribute__((address_space(3))) void*)(uintptr_t)l,
      16, 0, 0);
}

// ---------------------------------------------------------------------------
// GEMM: C[M,N] = A[M,K] @ B[N,K]^T  (A row stride = lda, B row stride = K)
// A, B bf16; C fp32 (MODE 0), fp32 + residual (MODE 1), bf16 (MODE 2).
// 128xBN tile (BN=128 or 64), BK=64, 4 waves, 16x16x32 MFMA, XOR-swizzled LDS.
// ---------------------------------------------------------------------------
template <int MODE, int BN>
__global__ __launch_bounds__(256) void gemm_bt(
    const u16* __restrict__ A, const u16* __restrict__ B,
    float* __restrict__ Cf, u16* __restrict__ Cb, const float* __restrict__ res,
    int M, int N, int K, int lda)
{
  constexpr int NI = BN / 32;          // acc cols per wave
  __shared__ __align__(16) u16 lsA[128 * 64];
  __shared__ __align__(16) u16 lsB[BN * 64];
  const int t = threadIdx.x;
  const int w = t >> 6, lane = t & 63;
  const int wm = (w >> 1) * 64, wn = (w & 1) * (BN / 2);
  const int lr = lane & 15, quad = lane >> 4;
  const int cswz = lr & 7;
  const size_t rowA0 = (size_t)blockIdx.x * 128;
  const size_t rowB0 = (size_t)blockIdx.y * BN;

  f32x4 acc[4][NI] = {};

  for (int k0 = 0; k0 < K; k0 += 64) {
#pragma unroll
    for (int i = 0; i < 4; ++i) {
      const int id = i * 256 + t;
      const int r = id >> 3;
      const int c = ((id & 7) ^ (r & 7)) * 8;  // swizzled source column
      cp16(A + (rowA0 + r) * lda + k0 + c, lsA + id * 8);
    }
#pragma unroll
    for (int i = 0; i < BN / 32; ++i) {
      const int id = i * 256 + t;
      const int r = id >> 3;
      const int c = ((id & 7) ^ (r & 7)) * 8;
      cp16(B + (rowB0 + r) * (size_t)K + k0 + c, lsB + id * 8);
    }
    __syncthreads();
#pragma unroll
    for (int ks = 0; ks < 2; ++ks) {
      const int co = ((ks * 4 + quad) ^ cswz) * 8;
      bf16x8 af[4], bfr[NI];
#pragma unroll
      for (int i = 0; i < 4; ++i)
        af[i] = *(const bf16x8*)(lsA + (wm + i * 16 + lr) * 64 + co);
#pragma unroll
      for (int i = 0; i < NI; ++i)
        bfr[i] = *(const bf16x8*)(lsB + (wn + i * 16 + lr) * 64 + co);
#pragma unroll
      for (int mi = 0; mi < 4; ++mi)
#pragma unroll
        for (int ni = 0; ni < NI; ++ni)
          acc[mi][ni] = __builtin_amdgcn_mfma_f32_16x16x32_bf16(
              af[mi], bfr[ni], acc[mi][ni], 0, 0, 0);
    }
    __syncthreads();
  }

#pragma unroll
  for (int mi = 0; mi < 4; ++mi) {
#pragma unroll
    for (int r = 0; r < 4; ++r) {
      const size_t m = rowA0 + wm + mi * 16 + quad * 4 + r;
#pragma unroll
      for (int ni = 0; ni < NI; ++ni) {
        const size_t n = rowB0 + wn + ni * 16 + lr;
        const size_t o = m * (size_t)N + n;
        const float v = acc[mi][ni][r];
        if (MODE == 0) Cf[o] = v;
        else if (MODE == 1) Cf[o] = v + res[o];
        else Cb[o] = f2b(v);
      }
    }
  }
}

// ---------------------------------------------------------------------------
// Fused up-proj + SwiGLU: H[4096][3072] = a * silu(g), where
// a = xn @ w_up[0:3072]^T, g = xn @ w_up[3072:6144]^T.
// Block tile 128m x 64j, staging BOTH a-rows and g-rows (128x64 B-tile).
// Dual accumulators; silu applied in registers; only h touches HBM.
// Grid (32, 48), LDS 32 KB.
// ---------------------------------------------------------------------------
__global__ __launch_bounds__(256) void gemm_up_swiglu_k(
    const u16* __restrict__ A, const u16* __restrict__ B, u16* __restrict__ H)
{
  __shared__ __align__(16) u16 lsA[128 * 64];
  __shared__ __align__(16) u16 lsB[128 * 64];  // rows [0,64)=a, [64,128)=g
  const int t = threadIdx.x;
  const int w = t >> 6, lane = t & 63;
  const int wm = (w >> 1) * 64, wn = (w & 1) * 32;
  const int lr = lane & 15, quad = lane >> 4;
  const int cswz = lr & 7;
  const size_t rowA0 = (size_t)blockIdx.x * 128;
  const int j0 = blockIdx.y * 64;

  f32x4 aa[4][2] = {}, ag[4][2] = {};

  for (int k0 = 0; k0 < 1024; k0 += 64) {
#pragma unroll
    for (int i = 0; i < 4; ++i) {
      const int id = i * 256 + t;
      const int r = id >> 3;
      const int c = ((id & 7) ^ (r & 7)) * 8;
      cp16(A + (rowA0 + r) * 1024 + k0 + c, lsA + id * 8);
    }
#pragma unroll
    for (int i = 0; i < 4; ++i) {
      const int id = i * 256 + t;
      const int r = id >> 3;
      const int c = ((id & 7) ^ (r & 7)) * 8;
      const int gr = (r < 64) ? (j0 + r) : (3072 + j0 + (r - 64));
      cp16(B + (size_t)gr * 1024 + k0 + c, lsB + id * 8);
    }
    __syncthreads();
#pragma unroll
    for (int ks = 0; ks < 2; ++ks) {
      const int co = ((ks * 4 + quad) ^ cswz) * 8;
      bf16x8 af[4], ba[2], bg[2];
#pragma unroll
      for (int i = 0; i < 4; ++i)
        af[i] = *(const bf16x8*)(lsA + (wm + i * 16 + lr) * 64 + co);
#pragma unroll
      for (int i = 0; i < 2; ++i) {
        ba[i] = *(const bf16x8*)(lsB + (wn + i * 16 + lr) * 64 + co);
        bg[i] = *(const bf16x8*)(lsB + (64 + wn + i * 16 + lr) * 64 + co);
      }
#pragma unroll
      for (int mi = 0; mi < 4; ++mi)
#pragma unroll
        for (int ni = 0; ni < 2; ++ni) {
          aa[mi][ni] = __builtin_amdgcn_mfma_f32_16x16x32_bf16(af[mi], ba[ni], aa[mi][ni], 0, 0, 0);
          ag[mi][ni] = __builtin_amdgcn_mfma_f32_16x16x32_bf16(af[mi], bg[ni], ag[mi][ni], 0, 0, 0);
        }
    }
    __syncthreads();
  }

#pragma unroll
  for (int mi = 0; mi < 4; ++mi) {
#pragma unroll
    for (int r = 0; r < 4; ++r) {
      const size_t m = rowA0 + wm + mi * 16 + quad * 4 + r;
#pragma unroll
      for (int ni = 0; ni < 2; ++ni) {
        const int j = j0 + wn + ni * 16 + lr;
        const float a = aa[mi][ni][r];
        const float g = ag[mi][ni][r];
        H[m * 3072 + j] = f2b(a * (g / (1.0f + __expf(-g))));
      }
    }
  }
}

// ---------------------------------------------------------------------------
// RMSNorm: one block per row of 1024; fp32 in, bf16 out.
// ---------------------------------------------------------------------------
__global__ __launch_bounds__(256) void rmsnorm_k(
    const float* __restrict__ x, const float* __restrict__ g, u16* __restrict__ out)
{
  const int row = blockIdx.x;
  const int t = threadIdx.x;
  const float4 a = ((const float4*)(x + (size_t)row * 1024))[t];
  float ss = a.x * a.x + a.y * a.y + a.z * a.z + a.w * a.w;
#pragma unroll
  for (int o = 32; o; o >>= 1) ss += __shfl_xor(ss, o, 64);
  __shared__ float red[4];
  if ((t & 63) == 0) red[t >> 6] = ss;
  __syncthreads();
  ss = red[0] + red[1] + red[2] + red[3];
  const float r = rsqrtf(ss * (1.0f / 1024.0f) + 1e-6f);
  const float4 gg = ((const float4*)g)[t];
  ushort4 o4;
  o4.x = f2b(a.x * gg.x * r);
  o4.y = f2b(a.y * gg.y * r);
  o4.z = f2b(a.z * gg.z * r);
  o4.w = f2b(a.w * gg.w * r);
  ((ushort4*)out)[(size_t)row * 256 + t] = o4;
}

// fp32 -> bf16 conversion of all four weight matrices in one launch.
// Block ranges: [0,3072)=w_qkv, [3072,4096)=w_out, [4096,10240)=w_up,
// [10240,13312)=w_down. 4 elems/thread.
__global__ __launch_bounds__(256) void cvt_all_k(
    const float* __restrict__ s0, const float* __restrict__ s1,
    const float* __restrict__ s2, const float* __restrict__ s3,
    u16* __restrict__ d0, u16* __restrict__ d1,
    u16* __restrict__ d2, u16* __restrict__ d3)
{
  const int b = blockIdx.x;
  const float* s; u16* d; int off;
  if (b < 3072)       { s = s0; d = d0; off = b; }
  else if (b < 4096)  { s = s1; d = d1; off = b - 3072; }
  else if (b < 10240) { s = s2; d = d2; off = b - 4096; }
  else                { s = s3; d = d3; off = b - 10240; }
  const size_t i = (size_t)off * 256 + threadIdx.x;
  const float4 v = ((const float4*)s)[i];
  ushort4 o4;
  o4.x = f2b(v.x); o4.y = f2b(v.y); o4.z = f2b(v.z); o4.w = f2b(v.w);
  ((ushort4*)d)[i] = o4;
}

// ---------------------------------------------------------------------------
// QKV prep (bf16 input): per (n,h,l) cosine-normalize q,k; write Q,K as
// [head][l][64] bf16, V transposed as [head][e][L] bf16 with k-PAIR-PERMUTED
// 64-blocks: within each 64-col block, stored 16B chunk c holds k-units
// 8*(c>>2)+(c&3) and +4 (unit = 4 consecutive k). This makes the attention
// V-fragment read a single b128 per (ei, k-half) -> conflict-free.
// Grid (L/64, nh, n), block 256.
// ---------------------------------------------------------------------------
__global__ __launch_bounds__(256) void qkv_prep_k(
    const u16* __restrict__ qkv, const float* __restrict__ attn_scale,
    u16* __restrict__ Qb, u16* __restrict__ Kb, u16* __restrict__ Vt)
{
  const int l0 = blockIdx.x * 64;
  const int h  = blockIdx.y;
  const int nb = blockIdx.z;
  const int t = threadIdx.x, w = t >> 6, lane = t & 63;
  __shared__ float lsV[64][65];  // +1 pad: conflict-free transposed reads
  const float sq = sqrtf(attn_scale[h]);
  const int head = nb * 16 + h;
#pragma unroll 4
  for (int i = 0; i < 16; ++i) {
    const int lrow = i * 4 + w;
    const int l = l0 + lrow;
    const u16* base = qkv + ((size_t)nb * 2048 + l) * 3072 + h * 64 + lane;
    const float qv = b2f(base[0]);
    const float kv = b2f(base[1024]);
    const float vv = b2f(base[2048]);
    float ssq = qv * qv, ssk = kv * kv;
#pragma unroll
    for (int o = 32; o; o >>= 1) {
      ssq += __shfl_xor(ssq, o, 64);
      ssk += __shfl_xor(ssk, o, 64);
    }
    const size_t gb = ((size_t)head * 2048 + l) * 64 + lane;
    Qb[gb] = f2b(qv * sq * rsqrtf(ssq + 1e-6f));
    Kb[gb] = f2b(kv * sq * rsqrtf(ssk + 1e-6f));
    lsV[lrow][lane] = vv;
  }
  __syncthreads();
  const int e = t >> 2, p = t & 3;
  union { u16 s[16]; uint4 v[2]; } tmp;
#pragma unroll
  for (int cc = 0; cc < 2; ++cc) {
    const int c = 2 * p + cc;
    const int kb = 32 * (c >> 2) + 4 * (c & 3);
#pragma unroll
    for (int i = 0; i < 4; ++i) {
      tmp.s[cc * 8 + i]     = f2b(lsV[kb + i][e]);
      tmp.s[cc * 8 + 4 + i] = f2b(lsV[kb + 16 + i][e]);
    }
  }
  u16* dst = Vt + ((size_t)head * 64 + e) * 2048 + l0 + p * 16;
  *(uint4*)dst = tmp.v[0];
  *(uint4*)(dst + 8) = tmp.v[1];
}

// ---------------------------------------------------------------------------
// Attention (r6 structure). Block = 64 q; wave w: q-half qh=w>>1, k-half
// kh=w&1 of each 64-k tile. S^T = K·Q^T (C-layout == B-operand of 16x16x16)
// feeds PV straight from registers; V-frags are single b128 thanks to the
// k-pair-permuted Vt. Partials merged across kh through LDS at the end.
// LDS: 2*(8K+8K) dbuf = 32 KB. Grid (32, 32) -> 4 blocks/CU.
// Scores bounded [-10,10] by cosine norm -> no max-tracking.
// ---------------------------------------------------------------------------
__global__ __launch_bounds__(256) void attn_k(
    const u16* __restrict__ Qb, const u16* __restrict__ Kb,
    const u16* __restrict__ Vt, u16* __restrict__ O)
{
  const int l0 = blockIdx.x * 64;
  const int head = blockIdx.y;
  const int nb = head >> 4, h = head & 15;
  const int t = threadIdx.x, w = t >> 6, lane = t & 63;
  const int lr = lane & 15, quad = lane >> 4;
  const int kh = w & 1, qh = w >> 1;
  __shared__ __align__(16) u16 lsKV[2][2][64 * 64];  // [buf][K=0/V=1]
  const size_t hb = (size_t)head << 17;  // head * 2048 * 64

  const int sr = t >> 3;
  const int sc = ((t & 7) ^ (sr & 7)) * 8;
  const u16* Kg = Kb + hb + (size_t)sr * 64 + sc;
  const u16* Vg = Vt + hb + (size_t)sr * 2048 + sc;

  // Q fragments (B-operand of S^T): q = l0 + qh*32 + qb*16 + lr, e = quad*8+j.
  bf16x8 qf[2][2];
#pragma unroll
  for (int qb = 0; qb < 2; ++qb) {
    const u16* qp = Qb + hb + (size_t)(l0 + qh * 32 + qb * 16 + lr) * 64 + quad * 8;
    qf[qb][0] = *(const bf16x8*)qp;
    qf[qb][1] = *(const bf16x8*)(qp + 32);
  }

  f32x4 ot[2][4] = {};    // O^T partial: ot[qb][ei][r] = O^T[ei*16+quad*4+r][q]
  float rs[2] = {0.f, 0.f};

  cp16(Kg, lsKV[0][0] + t * 8);
  cp16(Kg + 32 * 64, lsKV[0][0] + 32 * 64 + t * 8);
  cp16(Vg, lsKV[0][1] + t * 8);
  cp16(Vg + 32 * 2048, lsKV[0][1] + 32 * 64 + t * 8);

  int cur = 0;
  for (int k0 = 0; k0 < 2048; k0 += 64) {
    __syncthreads();  // buf[cur] staged; alt buf's readers done
    if (k0 + 64 < 2048) {
      const int nxt = cur ^ 1;
      const u16* Kn = Kg + (size_t)(k0 + 64) * 64;
      const u16* Vn = Vg + (k0 + 64);
      cp16(Kn, lsKV[nxt][0] + t * 8);
      cp16(Kn + 32 * 64, lsKV[nxt][0] + 32 * 64 + t * 8);
      cp16(Vn, lsKV[nxt][1] + t * 8);
      cp16(Vn + 32 * 2048, lsKV[nxt][1] + 32 * 64 + t * 8);
    }
    const u16* kb = lsKV[cur][0];
    const u16* vb = lsKV[cur][1];

    // S^T for this wave's k-half: kt = kh*2 + ktl
    s16x4 pf[2][2];  // [qb][ktl]
#pragma unroll
    for (int ktl = 0; ktl < 2; ++ktl) {
      const int kt = kh * 2 + ktl;
      const int krow = (kt * 16 + lr) * 64;
      const int kswz = lr & 7;
      const bf16x8 a0 = *(const bf16x8*)(kb + krow + ((quad ^ kswz) << 3));
      const bf16x8 a1 = *(const bf16x8*)(kb + krow + (((4 + quad) ^ kswz) << 3));
#pragma unroll
      for (int qb = 0; qb < 2; ++qb) {
        f32x4 s = {};
        s = __builtin_amdgcn_mfma_f32_16x16x32_bf16(a0, qf[qb][0], s, 0, 0, 0);
        s = __builtin_amdgcn_mfma_f32_16x16x32_bf16(a1, qf[qb][1], s, 0, 0, 0);
#pragma unroll
        for (int r = 0; r < 4; ++r) {
          const float p = __expf(s[r]);
          rs[qb] += p;
          pf[qb][ktl][r] = (short)f2b(p);
        }
      }
    }
    // PV: one b128 per ei gives V A-frags for BOTH ktl (k-pair-permuted Vt).
#pragma unroll
    for (int ei = 0; ei < 4; ++ei) {
      const int vrow = ei * 16 + lr;
      const s16x8 vv = *(const s16x8*)(vb + vrow * 64 + (((kh * 4 + quad) ^ (vrow & 7)) << 3));
      const s16x4 v0 = __builtin_shufflevector(vv, vv, 0, 1, 2, 3);
      const s16x4 v1 = __builtin_shufflevector(vv, vv, 4, 5, 6, 7);
#pragma unroll
      for (int qb = 0; qb < 2; ++qb) {
        ot[qb][ei] = __builtin_amdgcn_mfma_f32_16x16x16bf16_1k(v0, pf[qb][0], ot[qb][ei], 0, 0, 0);
        ot[qb][ei] = __builtin_amdgcn_mfma_f32_16x16x16bf16_1k(v1, pf[qb][1], ot[qb][ei], 0, 0, 0);
      }
    }
    cur ^= 1;
  }

  // intra-wave rowsum reduce across quads (lanes sharing q = lr)
#pragma unroll
  for (int qb = 0; qb < 2; ++qb) {
    rs[qb] += __shfl_xor(rs[qb], 16, 64);
    rs[qb] += __shfl_xor(rs[qb], 32, 64);
  }

  // merge k-halves: waves kh=1 publish partials, kh=0 finalize.
  __syncthreads();  // all tile reads done; LDS reusable
  float* mb = (float*)lsKV;  // (2 qh * 64 lanes) * 34 floats = 17.4 KB < 32 KB
  if (kh == 1) {
    float* dst = mb + (qh * 64 + lane) * 34;
#pragma unroll
    for (int qb = 0; qb < 2; ++qb)
#pragma unroll
      for (int ei = 0; ei < 4; ++ei)
#pragma unroll
        for (int r = 0; r < 4; ++r)
          dst[qb * 16 + ei * 4 + r] = ot[qb][ei][r];
    dst[32] = rs[0];
    dst[33] = rs[1];
  }
  __syncthreads();
  if (kh == 0) {
    const float* src = mb + (qh * 64 + lane) * 34;
#pragma unroll
    for (int qb = 0; qb < 2; ++qb) {
      const float inv = 1.0f / (rs[qb] + src[32 + qb]);
      u16* ob = O + ((size_t)nb * 2048 + l0 + qh * 32 + qb * 16 + lr) * 1024 + h * 64 + quad * 4;
#pragma unroll
      for (int ei = 0; ei < 4; ++ei) {
        ushort4 o4;
        o4.x = f2b((ot[qb][ei][0] + src[qb * 16 + ei * 4 + 0]) * inv);
        o4.y = f2b((ot[qb][ei][1] + src[qb * 16 + ei * 4 + 1]) * inv);
        o4.z = f2b((ot[qb][ei][2] + src[qb * 16 + ei * 4 + 2]) * inv);
        o4.w = f2b((ot[qb][ei][3] + src[qb * 16 + ei * 4 + 3]) * inv);
        *(ushort4*)(ob + ei * 16) = o4;
      }
    }
  }
}

// ---------------------------------------------------------------------------
// Workspace layout (bytes).
// ---------------------------------------------------------------------------
static constexpr size_t WQKV_B = 0;                            // 3072*1024*2
static constexpr size_t WOUT_B = WQKV_B + 6291456;             // 1024*1024*2
static constexpr size_t WUP_B  = WOUT_B + 2097152;             // 6144*1024*2
static constexpr size_t WDN_B  = WUP_B + 12582912;             // 1024*3072*2
static constexpr size_t XN_B   = WDN_B + 6291456;              // 4096*1024*2
static constexpr size_t Q_B    = XN_B + 8388608;               // 32*2048*64*2
static constexpr size_t K_B    = Q_B + 8388608;
static constexpr size_t VT_B   = K_B + 8388608;
static constexpr size_t O_B    = VT_B + 8388608;               // 4096*1024*2
static constexpr size_t BIG_B  = O_B + 8388608;                // qkv bf16 / h bf16
static constexpr size_t WS_NEED = BIG_B + 50331648;            // = 119537664

extern "C" void kernel_launch(void* const* d_in, const int* in_sizes, int n_in,
                              void* d_out, int out_size, void* d_ws, size_t ws_size,
                              hipStream_t stream)
{
  (void)in_sizes; (void)n_in; (void)out_size;
  if (ws_size < WS_NEED) {
    fprintf(stderr, "kernel_launch: ws_size %zu < required %zu\n", ws_size, WS_NEED);
    return;
  }
  const float* x          = (const float*)d_in[0];
  const float* norm_scale = (const float*)d_in[2];
  const float* w_qkv      = (const float*)d_in[3];
  const float* attn_scale = (const float*)d_in[4];
  const float* w_out      = (const float*)d_in[5];
  const float* ff_scale   = (const float*)d_in[6];
  const float* w_up       = (const float*)d_in[7];
  const float* w_down     = (const float*)d_in[8];
  float* out = (float*)d_out;
  char* ws = (char*)d_ws;

  u16* wqkv_b = (u16*)(ws + WQKV_B);
  u16* wout_b = (u16*)(ws + WOUT_B);
  u16* wup_b  = (u16*)(ws + WUP_B);
  u16* wdn_b  = (u16*)(ws + WDN_B);
  u16* xn     = (u16*)(ws + XN_B);
  u16* Qb     = (u16*)(ws + Q_B);
  u16* Kb     = (u16*)(ws + K_B);
  u16* Vtb    = (u16*)(ws + VT_B);
  u16* Ob     = (u16*)(ws + O_B);
  u16* qkvb   = (u16*)(ws + BIG_B);  // qkv bf16 (25 MB), later reused for h
  u16* hb     = (u16*)(ws + BIG_B);  // h bf16 4096x3072 (25 MB)

  // all weights fp32 -> bf16, one launch
  cvt_all_k<<<13312, 256, 0, stream>>>(w_qkv, w_out, w_up, w_down,
                                       wqkv_b, wout_b, wup_b, wdn_b);

  // xn = rmsnorm(x)
  rmsnorm_k<<<4096, 256, 0, stream>>>(x, norm_scale, xn);
  // qkv = xn @ w_qkv^T  (bf16 out)
  gemm_bt<2, 128><<<dim3(32, 24), 256, 0, stream>>>(xn, wqkv_b, nullptr, qkvb,
                                                    nullptr, 4096, 3072, 1024, 1024);
  // q/k cosine norm + head-major layouts + V transpose (k-pair-permuted)
  qkv_prep_k<<<dim3(32, 16, 2), 256, 0, stream>>>(qkvb, attn_scale, Qb, Kb, Vtb);
  // attention -> O bf16 [n][l][d]
  attn_k<<<dim3(32, 32), 256, 0, stream>>>(Qb, Kb, Vtb, Ob);
  // x1 = O @ w_out^T + x  -> d_out (fp32); BN=64 for occupancy (N=1024)
  gemm_bt<1, 64><<<dim3(32, 16), 256, 0, stream>>>(Ob, wout_b, out, nullptr, x,
                                                   4096, 1024, 1024, 1024);
  // xn = rmsnorm(x1)
  rmsnorm_k<<<4096, 256, 0, stream>>>(out, ff_scale, xn);
  // h = a * silu(g) fused with up-proj  (overwrites qkvb region)
  gemm_up_swiglu_k<<<dim3(32, 48), 256, 0, stream>>>(xn, wup_b, hb);
  // out = h @ w_down^T + x1  (in-place residual on d_out); BN=64
  gemm_bt<1, 64><<<dim3(32, 16), 256, 0, stream>>>(hb, wdn_b, out, nullptr, out,
                                                   4096, 1024, 3072, 3072);
}